// Round 14
// baseline (281.974 us; speedup 1.0000x reference)
//
#include <hip/hip_runtime.h>

#define NN 100000
#define NE 1600000
#define CIN 64
#define CH 128
#define NCLS 8
#define NG 1000

#define NBUCK 16
#define BUCK_NODES 6250                          // NN / 16 exactly
#define SUBS 8                                   // sub-partitions per bucket
#define NSUB (NBUCK * SUBS)                      // 128 build blocks
#define SUB_NODES 782                            // ceil(6250/8)
#define BCAP 102500                              // bucket capacity (mean 100000, +8 sigma)
#define CVT_GRID 1024
#define BUF 512                                  // LDS staging entries per bucket

typedef __attribute__((ext_vector_type(8))) short bf16x8;
typedef __attribute__((ext_vector_type(8))) unsigned short ushort8;
typedef __attribute__((ext_vector_type(4))) float f32x4;

__device__ __forceinline__ float bf2f(unsigned short u) {
    union { unsigned int i; float f; } c; c.i = ((unsigned int)u) << 16; return c.f;
}
__device__ __forceinline__ unsigned short f2bf(float f) {
    union { float f; unsigned int i; } c; c.f = f;
    unsigned int r = c.i + 0x7FFFu + ((c.i >> 16) & 1u);
    return (unsigned short)(r >> 16);
}

// Per-wave int64-vs-int32 detection: odd int32 slots are all zero iff int64.
__device__ __forceinline__ bool is_w64(const void* __restrict__ edge) {
    const int* e32 = (const int*)edge;
    int v = e32[2 * (threadIdx.x & 63) + 1];
    return __ballot(v != 0) == 0ull;
}

// ---------------- edge convert + radix partition by dst/6250 + batch ----------------
__global__ __launch_bounds__(256) void k_cvt_part(const void* __restrict__ edge, const void* __restrict__ batch,
                                                  unsigned* __restrict__ bucket, int* __restrict__ gcur,
                                                  int* __restrict__ bati) {
    __shared__ unsigned sbuf[NBUCK][BUF];
    __shared__ int scnt[NBUCK];
    __shared__ int sneed[NBUCK];
    __shared__ int sbase[NBUCK];
    const int tid = threadIdx.x;
    const bool w64 = is_w64(edge);
    if (tid < NBUCK) scnt[tid] = 0;
    __syncthreads();

    const int ntiles = (NE + 255) / 256;
    for (int t = blockIdx.x; t < ntiles; t += CVT_GRID) {
        const int i = t * 256 + tid;
        if (i < NE) {
            int s, d;
            if (w64) {
                const long long* e = (const long long*)edge;
                s = (int)e[i]; d = (int)e[NE + i];
            } else {
                const int* e = (const int*)edge;
                s = e[i]; d = e[NE + i];
            }
            const int q = d / BUCK_NODES;
            const unsigned v = ((unsigned)(d - q * BUCK_NODES) << 17) | (unsigned)s;
            int pos = atomicAdd(&scnt[q], 1);
            sbuf[q][pos] = v;
        }
        __syncthreads();
        if (tid < NBUCK) {
            int c = scnt[tid];
            int need = (c > BUF - 256) ? c : 0;
            sneed[tid] = need;
            if (need) { sbase[tid] = atomicAdd(&gcur[tid], need); scnt[tid] = 0; }
        }
        __syncthreads();
        for (int q = 0; q < NBUCK; q++) {
            int n = sneed[q];
            if (n) {
                unsigned* gb = bucket + (size_t)q * BCAP + sbase[q];
                for (int k = tid; k < n; k += 256) gb[k] = sbuf[q][k];
            }
        }
        __syncthreads();
    }
    // drain
    if (tid < NBUCK) {
        int c = scnt[tid];
        sneed[tid] = c;
        if (c) sbase[tid] = atomicAdd(&gcur[tid], c);
    }
    __syncthreads();
    for (int q = 0; q < NBUCK; q++) {
        int n = sneed[q];
        if (n) {
            unsigned* gb = bucket + (size_t)q * BCAP + sbase[q];
            for (int k = tid; k < n; k += 256) gb[k] = sbuf[q][k];
        }
    }
    // batch convert (strided across grid)
    const int idx0 = blockIdx.x * 256 + tid;
    const int stride = CVT_GRID * 256;
    if (w64) {
        const long long* b = (const long long*)batch;
        for (int i = idx0; i < NN; i += stride) bati[i] = (int)b[i];
    } else {
        const int* b = (const int*)batch;
        for (int i = idx0; i < NN; i += stride) bati[i] = b[i];
    }
}

// ---------------- fused CSR build: 128 blocks, sub-partition per block ----------------
__global__ __launch_bounds__(1024) void k_build(const unsigned* __restrict__ bucket, const int* __restrict__ gcur,
                                                int* __restrict__ rowstart, int* __restrict__ eidx) {
    __shared__ int cur[SUB_NODES];
    __shared__ int wsum[16];
    __shared__ int sbef;
    const int q = blockIdx.x >> 3;
    const int sub = blockIdx.x & 7;
    const int tid = threadIdx.x;
    const int lane = tid & 63;
    const int wid = tid >> 6;
    const int lo_local = sub * SUB_NODES;
    const int hi_local = min(BUCK_NODES, lo_local + SUB_NODES);
    const int n_nodes = hi_local - lo_local;
    const int node0 = q * BUCK_NODES + lo_local;
    const int cnt = gcur[q];
    const int cnt4 = cnt >> 2;
    int bbase = 0;
    for (int j = 0; j < q; j++) bbase += gcur[j];
    const unsigned* gb = bucket + (size_t)q * BCAP;
    const uint4* gb4 = (const uint4*)gb;

    for (int i = tid; i < SUB_NODES; i += 1024) cur[i] = 0;
    if (tid == 0) sbef = 0;
    __syncthreads();

    // pass 1: count own nodes + edges before this sub (base offset), uint4 stream
    int before = 0;
    for (int i = tid; i < cnt4; i += 1024) {
        uint4 u = gb4[i];
#pragma unroll
        for (int k = 0; k < 4; k++) {
            unsigned w = (k == 0) ? u.x : (k == 1) ? u.y : (k == 2) ? u.z : u.w;
            int dl = (int)(w >> 17);
            if (dl < lo_local) before++;
            else if (dl < hi_local) atomicAdd(&cur[dl - lo_local], 1);
        }
    }
    for (int i = cnt4 * 4 + tid; i < cnt; i += 1024) {
        int dl = (int)(gb[i] >> 17);
        if (dl < lo_local) before++;
        else if (dl < hi_local) atomicAdd(&cur[dl - lo_local], 1);
    }
#pragma unroll
    for (int s = 1; s < 64; s <<= 1) before += __shfl_xor(before, s, 64);
    if (lane == 0) atomicAdd(&sbef, before);
    __syncthreads();
    const int base = bbase + sbef;

    // exclusive scan of cur (in place) + write rowstart slice
    {
        const int i = tid;                         // SUB_NODES=782 < 1024: one tile
        const int v = (i < SUB_NODES) ? cur[i] : 0;
        int incl = v;
#pragma unroll
        for (int s = 1; s < 64; s <<= 1) {
            int u = __shfl_up(incl, s, 64);
            if (lane >= s) incl += u;
        }
        if (lane == 63) wsum[wid] = incl;
        __syncthreads();
        if (wid == 0) {
            int wv = (lane < 16) ? wsum[lane] : 0;
#pragma unroll
            for (int s = 1; s < 16; s <<= 1) {
                int u = __shfl_up(wv, s, 64);
                if (lane >= s) wv += u;
            }
            if (lane < 16) wsum[lane] = wv;   // inclusive scan of wave sums
        }
        __syncthreads();
        const int ebase = (wid ? wsum[wid - 1] : 0);
        const int excl = ebase + incl - v;
        __syncthreads();
        if (i < SUB_NODES) {
            if (i < n_nodes) rowstart[node0 + i] = base + excl;
            cur[i] = excl;
        }
        __syncthreads();
    }
    if (blockIdx.x == NSUB - 1 && tid == 0) rowstart[NN] = NE;

    // pass 2: fill, uint4 stream
    for (int i = tid; i < cnt4; i += 1024) {
        uint4 u = gb4[i];
#pragma unroll
        for (int k = 0; k < 4; k++) {
            unsigned w = (k == 0) ? u.x : (k == 1) ? u.y : (k == 2) ? u.z : u.w;
            int dl = (int)(w >> 17);
            if (dl >= lo_local && dl < hi_local) {
                int pos = base + atomicAdd(&cur[dl - lo_local], 1);
                eidx[pos] = (int)(w & 0x1FFFFu);
            }
        }
    }
    for (int i = cnt4 * 4 + tid; i < cnt; i += 1024) {
        unsigned w = gb[i];
        int dl = (int)(w >> 17);
        if (dl >= lo_local && dl < hi_local) {
            int pos = base + atomicAdd(&cur[dl - lo_local], 1);
            eidx[pos] = (int)(w & 0x1FFFFu);
        }
    }
}

// ---------------- fp32 -> bf16 feature conversion ----------------
__global__ void k_cvtx(const float* __restrict__ x, unsigned short* __restrict__ xb, int total8) {
    int i = blockIdx.x * blockDim.x + threadIdx.x;
    if (i >= total8) return;
    float4 v0 = ((const float4*)x)[2 * i];
    float4 v1 = ((const float4*)x)[2 * i + 1];
    ushort8 o;
    o[0] = f2bf(v0.x); o[1] = f2bf(v0.y); o[2] = f2bf(v0.z); o[3] = f2bf(v0.w);
    o[4] = f2bf(v1.x); o[5] = f2bf(v1.y); o[6] = f2bf(v1.z); o[7] = f2bf(v1.w);
    ((ushort8*)xb)[i] = o;
}

// ---------------- all four weights -> fragment-ready bf16, one kernel ----------------
__global__ void k_cvtWall(const float* __restrict__ W1l, const float* __restrict__ W1r,
                          const float* __restrict__ W2l, const float* __restrict__ W2r,
                          unsigned short* __restrict__ W1lf, unsigned short* __restrict__ W1rf,
                          unsigned short* __restrict__ W2lf, unsigned short* __restrict__ W2rf) {
    int idx = blockIdx.x * blockDim.x + threadIdx.x;   // 0..6143
    const float* W; unsigned short* out; int K; int local;
    if (idx < 1024)      { W = W1l; out = W1lf; K = 64;  local = idx; }
    else if (idx < 2048) { W = W1r; out = W1rf; K = 64;  local = idx - 1024; }
    else if (idx < 4096) { W = W2l; out = W2lf; K = 128; local = idx - 2048; }
    else                 { W = W2r; out = W2rf; K = 128; local = idx - 4096; }
    int l = local & 63;
    int ks = (local >> 6) % (K / 32);
    int nt = (local >> 6) / (K / 32);
    int krow = ks * 32 + (l >> 4) * 8;
    int col = nt * 16 + (l & 15);
    ushort8 o;
#pragma unroll
    for (int j = 0; j < 8; j++) o[j] = f2bf(W[(size_t)(krow + j) * 128 + col]);
    ((ushort8*)out)[local] = o;
}

// ---------------- FUSED gather-mean + SAGE MFMA ----------------
// out = relu(mean_gather(feat) @ B1 + feat @ B2 + bias).
// Gather happens directly in MFMA A-fragment layout: lane l of a wave owns
// row (l&15) of the wave's 16-row tile and k-chunk (l>>4); it accumulates
// mean of feat[src][ks*32 + (l>>4)*8 + j] over the row's in-edges into
// acc_g[KS][8] f32 regs, which after *inv and f2bf IS the A1 fragment.
// 16 independent edge streams per wave (vs 1 node/wave in the old gatherv),
// unroll-2 => up to 8x16B loads in flight per lane. No msgb materialization.
template <int K>
__global__ __launch_bounds__(256) void k_sage_fused(const unsigned short* __restrict__ feat,
                                                    const int* __restrict__ eidx,
                                                    const int* __restrict__ rowstart,
                                                    const unsigned short* __restrict__ B1,
                                                    const unsigned short* __restrict__ B2,
                                                    const float* __restrict__ bias,
                                                    unsigned short* __restrict__ out) {
    constexpr int KS = K / 32;
    const int wid = threadIdx.x >> 6;
    const int lane = threadIdx.x & 63;
    const int rowbase = blockIdx.x * 64 + wid * 16;
    const int arow = rowbase + (lane & 15);
    const int arowc = (arow < NN) ? arow : (NN - 1);
    const int kgrp = (lane >> 4) * 8;

    // ---- gather-mean into A1 fragment accumulators ----
    float acc_g[KS][8];
#pragma unroll
    for (int ks = 0; ks < KS; ks++)
#pragma unroll
        for (int j = 0; j < 8; j++) acc_g[ks][j] = 0.f;

    const int lo = rowstart[arowc];
    const int hi = rowstart[arowc + 1];
    int e = lo;
    for (; e + 1 < hi; e += 2) {
        const int s0 = eidx[e];
        const int s1 = eidx[e + 1];
        const unsigned short* r0 = &feat[(size_t)s0 * K + kgrp];
        const unsigned short* r1 = &feat[(size_t)s1 * K + kgrp];
#pragma unroll
        for (int ks = 0; ks < KS; ks++) {
            ushort8 v0 = *(const ushort8*)(r0 + ks * 32);
            ushort8 v1 = *(const ushort8*)(r1 + ks * 32);
#pragma unroll
            for (int j = 0; j < 8; j++) acc_g[ks][j] += bf2f(v0[j]) + bf2f(v1[j]);
        }
    }
    if (e < hi) {
        const int s0 = eidx[e];
        const unsigned short* r0 = &feat[(size_t)s0 * K + kgrp];
#pragma unroll
        for (int ks = 0; ks < KS; ks++) {
            ushort8 v0 = *(const ushort8*)(r0 + ks * 32);
#pragma unroll
            for (int j = 0; j < 8; j++) acc_g[ks][j] += bf2f(v0[j]);
        }
    }
    const float inv = 1.0f / fmaxf((float)(hi - lo), 1.0f);

    union { ushort8 u; bf16x8 b; } a1[KS];
#pragma unroll
    for (int ks = 0; ks < KS; ks++)
#pragma unroll
        for (int j = 0; j < 8; j++) a1[ks].u[j] = f2bf(acc_g[ks][j] * inv);

    // ---- MFMA: acc = A1@B1 + A2@B2 + bias ----
    f32x4 acc[8];
#pragma unroll
    for (int nt = 0; nt < 8; nt++) {
        float bj = bias[nt * 16 + (lane & 15)];
        acc[nt][0] = bj; acc[nt][1] = bj; acc[nt][2] = bj; acc[nt][3] = bj;
    }

    const bf16x8* b1v = (const bf16x8*)B1;
    const bf16x8* b2v = (const bf16x8*)B2;
#pragma unroll
    for (int ks = 0; ks < KS; ks++) {
        bf16x8 a2 = *(const bf16x8*)&feat[(size_t)arowc * K + ks * 32 + kgrp];
#pragma unroll
        for (int nt = 0; nt < 8; nt++) {
            acc[nt] = __builtin_amdgcn_mfma_f32_16x16x32_bf16(a1[ks].b, b1v[(nt * KS + ks) * 64 + lane], acc[nt], 0, 0, 0);
            acc[nt] = __builtin_amdgcn_mfma_f32_16x16x32_bf16(a2, b2v[(nt * KS + ks) * 64 + lane], acc[nt], 0, 0, 0);
        }
    }

    const int colb = lane & 15;
    const int rhi = (lane >> 4) * 4;
#pragma unroll
    for (int nt = 0; nt < 8; nt++) {
#pragma unroll
        for (int r = 0; r < 4; r++) {
            int row = rowbase + rhi + r;
            if (row < NN)
                out[(size_t)row * 128 + nt * 16 + colb] = f2bf(fmaxf(acc[nt][r], 0.0f));
        }
    }
}

// ---------------- fused global-mean-pool + head (bf16 h, fp32 math) ----------------
__device__ __forceinline__ int lower_bound_dev(const int* __restrict__ a, int n, int key) {
    int lo = 0, hi = n;
    while (lo < hi) {
        int mid = (lo + hi) >> 1;
        if (a[mid] < key) lo = mid + 1; else hi = mid;
    }
    return lo;
}

__global__ __launch_bounds__(128) void k_poolb(const unsigned short* __restrict__ h,
                                               const int* __restrict__ batch,
                                               const float* __restrict__ Wh, const float* __restrict__ bh,
                                               float* __restrict__ out) {
    const int g = blockIdx.x;
    const int lo = lower_bound_dev(batch, NN, g);
    const int hi = lower_bound_dev(batch, NN, g + 1);
    const int j = threadIdx.x;
    float s = 0.f;
    for (int i = lo; i < hi; i++) s += bf2f(h[(size_t)i * CH + j]);
    __shared__ float pooled[CH];
    pooled[j] = s / fmaxf((float)(hi - lo), 1.0f);
    __syncthreads();
    if (j < NCLS) {
        float acc = bh[j];
#pragma unroll
        for (int k = 0; k < CH; k++) acc = fmaf(pooled[k], Wh[k * NCLS + j], acc);
        out[(size_t)g * NCLS + j] = acc;
    }
}

extern "C" void kernel_launch(void* const* d_in, const int* in_sizes, int n_in,
                              void* d_out, int out_size, void* d_ws, size_t ws_size,
                              hipStream_t stream) {
    const float* x   = (const float*)d_in[0];
    const void* edge = d_in[1];
    const void* batch= d_in[2];
    const float* W1l = (const float*)d_in[3];
    const float* W1r = (const float*)d_in[4];
    const float* b1  = (const float*)d_in[5];
    const float* W2l = (const float*)d_in[6];
    const float* W2r = (const float*)d_in[7];
    const float* b2  = (const float*)d_in[8];
    const float* Wh  = (const float*)d_in[9];
    const float* bh  = (const float*)d_in[10];
    float* out = (float*)d_out;

    char* p = (char*)d_ws;
    unsigned short* xb   = (unsigned short*)p; p += (size_t)NN * CIN * 2;   // 12.8 MB
    unsigned short* h1b  = (unsigned short*)p; p += (size_t)NN * CH * 2;    // 25.6 MB
    unsigned short* h2b  = (unsigned short*)p; p += (size_t)NN * CH * 2;    // 25.6 MB
    unsigned short* W1lf = (unsigned short*)p; p += (size_t)CIN * CH * 2;
    unsigned short* W1rf = (unsigned short*)p; p += (size_t)CIN * CH * 2;
    unsigned short* W2lf = (unsigned short*)p; p += (size_t)CH * CH * 2;
    unsigned short* W2rf = (unsigned short*)p; p += (size_t)CH * CH * 2;
    int* bati  = (int*)p;       p += (size_t)NN * sizeof(int);
    int* gcur  = (int*)p;       p += NBUCK * sizeof(int);                   // zeroed
    int* rowstart = (int*)p;    p += (size_t)(NN + 1) * sizeof(int) + 12;   // keep 16B align below
    unsigned* bucket = (unsigned*)p; p += (size_t)NBUCK * BCAP * sizeof(unsigned); // 6.6 MB
    int* eidx  = (int*)p;       p += (size_t)NE * sizeof(int);              // 6.4 MB

    hipMemsetAsync(gcur, 0, NBUCK * sizeof(int), stream);
    k_cvt_part<<<CVT_GRID, 256, 0, stream>>>(edge, batch, bucket, gcur, bati);
    k_build<<<NSUB, 1024, 0, stream>>>(bucket, gcur, rowstart, eidx);

    // conversions (independent of CSR build)
    k_cvtx<<<(NN * CIN / 8 + 255) / 256, 256, 0, stream>>>(x, xb, NN * CIN / 8);
    k_cvtWall<<<24, 256, 0, stream>>>(W1l, W1r, W2l, W2r, W1lf, W1rf, W2lf, W2rf);

    // layer 1 (fused gather+GEMM), layer 2 (fused gather+GEMM)
    k_sage_fused<CIN><<<(NN + 63) / 64, 256, 0, stream>>>(xb, eidx, rowstart, W1lf, W1rf, b1, h1b);
    k_sage_fused<CH><<<(NN + 63) / 64, 256, 0, stream>>>(h1b, eidx, rowstart, W2lf, W2rf, b2, h2b);

    k_poolb<<<NG, 128, 0, stream>>>(h2b, bati, Wh, bh, out);
}

// Round 15
// 259.813 us; speedup vs baseline: 1.0853x; 1.0853x over previous
//
#include <hip/hip_runtime.h>

#define NN 100000
#define NE 1600000
#define CIN 64
#define CH 128
#define NCLS 8
#define NG 1000

#define NBUCK 16
#define BUCK_NODES 6250                          // NN / 16 exactly
#define SUBS 8                                   // sub-partitions per bucket
#define NSUB (NBUCK * SUBS)                      // 128 build blocks
#define SUB_NODES 782                            // ceil(6250/8)
#define BCAP 102500                              // bucket capacity (mean 100000, +8 sigma)
#define CVT_GRID 1024
#define BUF 512                                  // LDS staging entries per bucket

typedef __attribute__((ext_vector_type(8))) short bf16x8;
typedef __attribute__((ext_vector_type(8))) unsigned short ushort8;
typedef __attribute__((ext_vector_type(4))) float f32x4;

__device__ __forceinline__ float bf2f(unsigned short u) {
    union { unsigned int i; float f; } c; c.i = ((unsigned int)u) << 16; return c.f;
}
__device__ __forceinline__ unsigned short f2bf(float f) {
    union { float f; unsigned int i; } c; c.f = f;
    unsigned int r = c.i + 0x7FFFu + ((c.i >> 16) & 1u);
    return (unsigned short)(r >> 16);
}

// Per-wave int64-vs-int32 detection: odd int32 slots are all zero iff int64.
__device__ __forceinline__ bool is_w64(const void* __restrict__ edge) {
    const int* e32 = (const int*)edge;
    int v = e32[2 * (threadIdx.x & 63) + 1];
    return __ballot(v != 0) == 0ull;
}

// ---------------- edge convert + radix partition by dst/6250 + batch + x->bf16 ----------------
__global__ __launch_bounds__(256) void k_cvt_part(const void* __restrict__ edge, const void* __restrict__ batch,
                                                  const float* __restrict__ x,
                                                  unsigned* __restrict__ bucket, int* __restrict__ gcur,
                                                  int* __restrict__ bati, unsigned short* __restrict__ xb) {
    __shared__ unsigned sbuf[NBUCK][BUF];
    __shared__ int scnt[NBUCK];
    __shared__ int sneed[NBUCK];
    __shared__ int sbase[NBUCK];
    const int tid = threadIdx.x;
    const bool w64 = is_w64(edge);
    if (tid < NBUCK) scnt[tid] = 0;
    __syncthreads();

    const int ntiles = (NE + 255) / 256;
    for (int t = blockIdx.x; t < ntiles; t += CVT_GRID) {
        const int i = t * 256 + tid;
        if (i < NE) {
            int s, d;
            if (w64) {
                const long long* e = (const long long*)edge;
                s = (int)e[i]; d = (int)e[NE + i];
            } else {
                const int* e = (const int*)edge;
                s = e[i]; d = e[NE + i];
            }
            const int q = d / BUCK_NODES;
            const unsigned v = ((unsigned)(d - q * BUCK_NODES) << 17) | (unsigned)s;
            int pos = atomicAdd(&scnt[q], 1);
            sbuf[q][pos] = v;
        }
        __syncthreads();
        if (tid < NBUCK) {
            int c = scnt[tid];
            int need = (c > BUF - 256) ? c : 0;
            sneed[tid] = need;
            if (need) { sbase[tid] = atomicAdd(&gcur[tid], need); scnt[tid] = 0; }
        }
        __syncthreads();
        for (int q = 0; q < NBUCK; q++) {
            int n = sneed[q];
            if (n) {
                unsigned* gb = bucket + (size_t)q * BCAP + sbase[q];
                for (int k = tid; k < n; k += 256) gb[k] = sbuf[q][k];
            }
        }
        __syncthreads();
    }
    // drain
    if (tid < NBUCK) {
        int c = scnt[tid];
        sneed[tid] = c;
        if (c) sbase[tid] = atomicAdd(&gcur[tid], c);
    }
    __syncthreads();
    for (int q = 0; q < NBUCK; q++) {
        int n = sneed[q];
        if (n) {
            unsigned* gb = bucket + (size_t)q * BCAP + sbase[q];
            for (int k = tid; k < n; k += 256) gb[k] = sbuf[q][k];
        }
    }
    // batch convert + x -> bf16 (strided across grid)
    const int idx0 = blockIdx.x * 256 + tid;
    const int stride = CVT_GRID * 256;
    if (w64) {
        const long long* b = (const long long*)batch;
        for (int i = idx0; i < NN; i += stride) bati[i] = (int)b[i];
    } else {
        const int* b = (const int*)batch;
        for (int i = idx0; i < NN; i += stride) bati[i] = b[i];
    }
    const int total8 = NN * CIN / 8;
    for (int i = idx0; i < total8; i += stride) {
        float4 v0 = ((const float4*)x)[2 * i];
        float4 v1 = ((const float4*)x)[2 * i + 1];
        ushort8 o;
        o[0] = f2bf(v0.x); o[1] = f2bf(v0.y); o[2] = f2bf(v0.z); o[3] = f2bf(v0.w);
        o[4] = f2bf(v1.x); o[5] = f2bf(v1.y); o[6] = f2bf(v1.z); o[7] = f2bf(v1.w);
        ((ushort8*)xb)[i] = o;
    }
}

// ---------------- fused CSR build: 128 blocks, sub-partition per block ----------------
__global__ __launch_bounds__(1024) void k_build(const unsigned* __restrict__ bucket, const int* __restrict__ gcur,
                                                int* __restrict__ rowstart, int* __restrict__ eidx) {
    __shared__ int cur[SUB_NODES];
    __shared__ int wsum[16];
    __shared__ int sbef;
    const int q = blockIdx.x >> 3;
    const int sub = blockIdx.x & 7;
    const int tid = threadIdx.x;
    const int lane = tid & 63;
    const int wid = tid >> 6;
    const int lo_local = sub * SUB_NODES;
    const int hi_local = min(BUCK_NODES, lo_local + SUB_NODES);
    const int n_nodes = hi_local - lo_local;
    const int node0 = q * BUCK_NODES + lo_local;
    const int cnt = gcur[q];
    const int cnt4 = cnt >> 2;
    int bbase = 0;
    for (int j = 0; j < q; j++) bbase += gcur[j];
    const unsigned* gb = bucket + (size_t)q * BCAP;
    const uint4* gb4 = (const uint4*)gb;

    for (int i = tid; i < SUB_NODES; i += 1024) cur[i] = 0;
    if (tid == 0) sbef = 0;
    __syncthreads();

    // pass 1: count own nodes + edges before this sub (base offset), uint4 stream
    int before = 0;
    for (int i = tid; i < cnt4; i += 1024) {
        uint4 u = gb4[i];
#pragma unroll
        for (int k = 0; k < 4; k++) {
            unsigned w = (k == 0) ? u.x : (k == 1) ? u.y : (k == 2) ? u.z : u.w;
            int dl = (int)(w >> 17);
            if (dl < lo_local) before++;
            else if (dl < hi_local) atomicAdd(&cur[dl - lo_local], 1);
        }
    }
    for (int i = cnt4 * 4 + tid; i < cnt; i += 1024) {
        int dl = (int)(gb[i] >> 17);
        if (dl < lo_local) before++;
        else if (dl < hi_local) atomicAdd(&cur[dl - lo_local], 1);
    }
#pragma unroll
    for (int s = 1; s < 64; s <<= 1) before += __shfl_xor(before, s, 64);
    if (lane == 0) atomicAdd(&sbef, before);
    __syncthreads();
    const int base = bbase + sbef;

    // exclusive scan of cur (in place) + write rowstart slice
    {
        const int i = tid;                         // SUB_NODES=782 < 1024: one tile
        const int v = (i < SUB_NODES) ? cur[i] : 0;
        int incl = v;
#pragma unroll
        for (int s = 1; s < 64; s <<= 1) {
            int u = __shfl_up(incl, s, 64);
            if (lane >= s) incl += u;
        }
        if (lane == 63) wsum[wid] = incl;
        __syncthreads();
        if (wid == 0) {
            int wv = (lane < 16) ? wsum[lane] : 0;
#pragma unroll
            for (int s = 1; s < 16; s <<= 1) {
                int u = __shfl_up(wv, s, 64);
                if (lane >= s) wv += u;
            }
            if (lane < 16) wsum[lane] = wv;   // inclusive scan of wave sums
        }
        __syncthreads();
        const int ebase = (wid ? wsum[wid - 1] : 0);
        const int excl = ebase + incl - v;
        __syncthreads();
        if (i < SUB_NODES) {
            if (i < n_nodes) rowstart[node0 + i] = base + excl;
            cur[i] = excl;
        }
        __syncthreads();
    }
    if (blockIdx.x == NSUB - 1 && tid == 0) rowstart[NN] = NE;

    // pass 2: fill, uint4 stream
    for (int i = tid; i < cnt4; i += 1024) {
        uint4 u = gb4[i];
#pragma unroll
        for (int k = 0; k < 4; k++) {
            unsigned w = (k == 0) ? u.x : (k == 1) ? u.y : (k == 2) ? u.z : u.w;
            int dl = (int)(w >> 17);
            if (dl >= lo_local && dl < hi_local) {
                int pos = base + atomicAdd(&cur[dl - lo_local], 1);
                eidx[pos] = (int)(w & 0x1FFFFu);
            }
        }
    }
    for (int i = cnt4 * 4 + tid; i < cnt; i += 1024) {
        unsigned w = gb[i];
        int dl = (int)(w >> 17);
        if (dl >= lo_local && dl < hi_local) {
            int pos = base + atomicAdd(&cur[dl - lo_local], 1);
            eidx[pos] = (int)(w & 0x1FFFFu);
        }
    }
}

// ---------------- all four weights -> fragment-ready bf16, one kernel ----------------
__global__ void k_cvtWall(const float* __restrict__ W1l, const float* __restrict__ W1r,
                          const float* __restrict__ W2l, const float* __restrict__ W2r,
                          unsigned short* __restrict__ W1lf, unsigned short* __restrict__ W1rf,
                          unsigned short* __restrict__ W2lf, unsigned short* __restrict__ W2rf) {
    int idx = blockIdx.x * blockDim.x + threadIdx.x;   // 0..6143
    const float* W; unsigned short* out; int K; int local;
    if (idx < 1024)      { W = W1l; out = W1lf; K = 64;  local = idx; }
    else if (idx < 2048) { W = W1r; out = W1rf; K = 64;  local = idx - 1024; }
    else if (idx < 4096) { W = W2l; out = W2lf; K = 128; local = idx - 2048; }
    else                 { W = W2r; out = W2rf; K = 128; local = idx - 4096; }
    int l = local & 63;
    int ks = (local >> 6) % (K / 32);
    int nt = (local >> 6) / (K / 32);
    int krow = ks * 32 + (l >> 4) * 8;
    int col = nt * 16 + (l & 15);
    ushort8 o;
#pragma unroll
    for (int j = 0; j < 8; j++) o[j] = f2bf(W[(size_t)(krow + j) * 128 + col]);
    ((ushort8*)out)[local] = o;
}

// ---------------- gather-mean over in-edges, vectorized, unroll-4 ----------------
template <int C>
__global__ __launch_bounds__(256) void k_gatherv(const unsigned short* __restrict__ feat,
                                                 const int* __restrict__ eidx,
                                                 const int* __restrict__ rowstart,
                                                 unsigned short* __restrict__ msg) {
    constexpr int G = C / 8;          // lanes per row: 8 (C=64) or 16 (C=128)
    constexpr int EPW = 64 / G;       // edge streams per wave: 8 or 4
    const int node = blockIdx.x * 4 + (threadIdx.x >> 6);
    if (node >= NN) return;
    const int lane = threadIdx.x & 63;
    const int grp = lane / G;
    const int sub = lane % G;
    const int lo = rowstart[node];
    const int hi = rowstart[node + 1];

    float acc[8] = {0.f, 0.f, 0.f, 0.f, 0.f, 0.f, 0.f, 0.f};
    int e = lo + grp;
    // unroll-4: four independent row loads in flight per group
    for (; e + 3 * EPW < hi; e += 4 * EPW) {
        int s0 = eidx[e];
        int s1 = eidx[e + EPW];
        int s2 = eidx[e + 2 * EPW];
        int s3 = eidx[e + 3 * EPW];
        ushort8 v0 = *(const ushort8*)&feat[(size_t)s0 * C + sub * 8];
        ushort8 v1 = *(const ushort8*)&feat[(size_t)s1 * C + sub * 8];
        ushort8 v2 = *(const ushort8*)&feat[(size_t)s2 * C + sub * 8];
        ushort8 v3 = *(const ushort8*)&feat[(size_t)s3 * C + sub * 8];
#pragma unroll
        for (int j = 0; j < 8; j++)
            acc[j] += (bf2f(v0[j]) + bf2f(v1[j])) + (bf2f(v2[j]) + bf2f(v3[j]));
    }
    for (; e < hi; e += EPW) {
        int s0 = eidx[e];
        ushort8 v0 = *(const ushort8*)&feat[(size_t)s0 * C + sub * 8];
#pragma unroll
        for (int j = 0; j < 8; j++) acc[j] += bf2f(v0[j]);
    }

#pragma unroll
    for (int off = G; off < 64; off <<= 1) {
#pragma unroll
        for (int j = 0; j < 8; j++) acc[j] += __shfl_xor(acc[j], off, 64);
    }

    if (grp == 0) {
        const float inv = 1.0f / fmaxf((float)(hi - lo), 1.0f);
        ushort8 o;
#pragma unroll
        for (int j = 0; j < 8; j++) o[j] = f2bf(acc[j] * inv);
        *(ushort8*)&msg[(size_t)node * C + sub * 8] = o;
    }
}

// ---------------- fused SAGE layer via MFMA: out = relu(A1@B1 + A2@B2 + bias) ----------------
template <int K>
__global__ __launch_bounds__(256) void k_sage_mfma(const unsigned short* __restrict__ A1,
                                                   const unsigned short* __restrict__ A2,
                                                   const unsigned short* __restrict__ B1,
                                                   const unsigned short* __restrict__ B2,
                                                   const float* __restrict__ bias,
                                                   unsigned short* __restrict__ out) {
    constexpr int KS = K / 32;
    const int wid = threadIdx.x >> 6;
    const int lane = threadIdx.x & 63;
    const int rowbase = blockIdx.x * 64 + wid * 16;
    const int arow = rowbase + (lane & 15);
    const int arowc = (arow < NN) ? arow : (NN - 1);
    const int kgrp = (lane >> 4) * 8;

    f32x4 acc[8];
#pragma unroll
    for (int nt = 0; nt < 8; nt++) {
        float bj = bias[nt * 16 + (lane & 15)];
        acc[nt][0] = bj; acc[nt][1] = bj; acc[nt][2] = bj; acc[nt][3] = bj;
    }

    const bf16x8* b1v = (const bf16x8*)B1;
    const bf16x8* b2v = (const bf16x8*)B2;
#pragma unroll
    for (int ks = 0; ks < KS; ks++) {
        bf16x8 a1 = *(const bf16x8*)&A1[(size_t)arowc * K + ks * 32 + kgrp];
        bf16x8 a2 = *(const bf16x8*)&A2[(size_t)arowc * K + ks * 32 + kgrp];
#pragma unroll
        for (int nt = 0; nt < 8; nt++) {
            acc[nt] = __builtin_amdgcn_mfma_f32_16x16x32_bf16(a1, b1v[(nt * KS + ks) * 64 + lane], acc[nt], 0, 0, 0);
            acc[nt] = __builtin_amdgcn_mfma_f32_16x16x32_bf16(a2, b2v[(nt * KS + ks) * 64 + lane], acc[nt], 0, 0, 0);
        }
    }

    const int colb = lane & 15;
    const int rhi = (lane >> 4) * 4;
#pragma unroll
    for (int nt = 0; nt < 8; nt++) {
#pragma unroll
        for (int r = 0; r < 4; r++) {
            int row = rowbase + rhi + r;
            if (row < NN)
                out[(size_t)row * 128 + nt * 16 + colb] = f2bf(fmaxf(acc[nt][r], 0.0f));
        }
    }
}

// ---------------- fused global-mean-pool + head (bf16 h, fp32 math) ----------------
__device__ __forceinline__ int lower_bound_dev(const int* __restrict__ a, int n, int key) {
    int lo = 0, hi = n;
    while (lo < hi) {
        int mid = (lo + hi) >> 1;
        if (a[mid] < key) lo = mid + 1; else hi = mid;
    }
    return lo;
}

__global__ __launch_bounds__(128) void k_poolb(const unsigned short* __restrict__ h,
                                               const int* __restrict__ batch,
                                               const float* __restrict__ Wh, const float* __restrict__ bh,
                                               float* __restrict__ out) {
    const int g = blockIdx.x;
    const int lo = lower_bound_dev(batch, NN, g);
    const int hi = lower_bound_dev(batch, NN, g + 1);
    const int j = threadIdx.x;
    float s = 0.f;
    for (int i = lo; i < hi; i++) s += bf2f(h[(size_t)i * CH + j]);
    __shared__ float pooled[CH];
    pooled[j] = s / fmaxf((float)(hi - lo), 1.0f);
    __syncthreads();
    if (j < NCLS) {
        float acc = bh[j];
#pragma unroll
        for (int k = 0; k < CH; k++) acc = fmaf(pooled[k], Wh[k * NCLS + j], acc);
        out[(size_t)g * NCLS + j] = acc;
    }
}

extern "C" void kernel_launch(void* const* d_in, const int* in_sizes, int n_in,
                              void* d_out, int out_size, void* d_ws, size_t ws_size,
                              hipStream_t stream) {
    const float* x   = (const float*)d_in[0];
    const void* edge = d_in[1];
    const void* batch= d_in[2];
    const float* W1l = (const float*)d_in[3];
    const float* W1r = (const float*)d_in[4];
    const float* b1  = (const float*)d_in[5];
    const float* W2l = (const float*)d_in[6];
    const float* W2r = (const float*)d_in[7];
    const float* b2  = (const float*)d_in[8];
    const float* Wh  = (const float*)d_in[9];
    const float* bh  = (const float*)d_in[10];
    float* out = (float*)d_out;

    char* p = (char*)d_ws;
    unsigned short* xb   = (unsigned short*)p; p += (size_t)NN * CIN * 2;   // 12.8 MB
    unsigned short* h1b  = (unsigned short*)p; p += (size_t)NN * CH * 2;    // 25.6 MB
    unsigned short* h2b  = (unsigned short*)p; p += (size_t)NN * CH * 2;    // 25.6 MB
    unsigned short* msgb = (unsigned short*)p; p += (size_t)NN * CH * 2;    // 25.6 MB
    unsigned short* W1lf = (unsigned short*)p; p += (size_t)CIN * CH * 2;
    unsigned short* W1rf = (unsigned short*)p; p += (size_t)CIN * CH * 2;
    unsigned short* W2lf = (unsigned short*)p; p += (size_t)CH * CH * 2;
    unsigned short* W2rf = (unsigned short*)p; p += (size_t)CH * CH * 2;
    int* bati  = (int*)p;       p += (size_t)NN * sizeof(int);
    int* gcur  = (int*)p;       p += NBUCK * sizeof(int);                   // zeroed
    int* rowstart = (int*)p;    p += (size_t)(NN + 1) * sizeof(int) + 12;   // keep 16B align below
    unsigned* bucket = (unsigned*)p; p += (size_t)NBUCK * BCAP * sizeof(unsigned); // 6.6 MB
    int* eidx  = (int*)p;       p += (size_t)NE * sizeof(int);              // 6.4 MB

    hipMemsetAsync(gcur, 0, NBUCK * sizeof(int), stream);
    k_cvt_part<<<CVT_GRID, 256, 0, stream>>>(edge, batch, x, bucket, gcur, bati, xb);
    k_build<<<NSUB, 1024, 0, stream>>>(bucket, gcur, rowstart, eidx);
    k_cvtWall<<<24, 256, 0, stream>>>(W1l, W1r, W2l, W2r, W1lf, W1rf, W2lf, W2rf);

    // layer 1
    k_gatherv<CIN><<<(NN + 3) / 4, 256, 0, stream>>>(xb, eidx, rowstart, msgb);
    k_sage_mfma<CIN><<<(NN + 63) / 64, 256, 0, stream>>>(msgb, xb, W1lf, W1rf, b1, h1b);

    // layer 2
    k_gatherv<CH><<<(NN + 3) / 4, 256, 0, stream>>>(h1b, eidx, rowstart, msgb);
    k_sage_mfma<CH><<<(NN + 63) / 64, 256, 0, stream>>>(msgb, h1b, W2lf, W2rf, b2, h2b);

    k_poolb<<<NG, 128, 0, stream>>>(h2b, bati, Wh, bh, out);
}